// Round 11
// baseline (196.940 us; speedup 1.0000x reference)
//
#include <hip/hip_runtime.h>
#include <hip/hip_bf16.h>

// B=1024, S=200, IN1=IN2=H=128
constexpr int S_ = 200;
constexpr int SP = 208;

typedef __attribute__((ext_vector_type(8))) short short8_t;
typedef __attribute__((ext_vector_type(4))) float float4_t;

__device__ inline unsigned short f2bf(float f) {
  unsigned int u = __float_as_uint(f);
  u += 0x7FFFu + ((u >> 16) & 1u);   // RTE
  return (unsigned short)(u >> 16);
}
__device__ inline unsigned int pk2(float x, float y) {
  return (unsigned int)f2bf(x) | ((unsigned int)f2bf(y) << 16);
}

// ---- k0: pack W1 into bf16 MFMA B-fragments (32 KB of ws). 8 blocks x 256. ----
// frag[fid], fid = nh*256 + kk*64 + lane; lane=(kb<<4)|c; elem j: k=kk*32+kb*8+j,
// h = nh*16 + c; value = bf16(W1[k][h]).
__global__ __launch_bounds__(256) void prep_frag_kernel(
    const float* __restrict__ W1, short8_t* __restrict__ frag_out) {
  const int fid = blockIdx.x * 256 + threadIdx.x;   // 0..2047
  const int lane = fid & 63, kk = (fid >> 6) & 3, nh = fid >> 8;
  const int c = lane & 15, kb = lane >> 4;
  const int h = nh * 16 + c;
  union { short8_t s8; unsigned int u[4]; } cv;
  #pragma unroll
  for (int jp = 0; jp < 4; ++jp) {
    const int k = kk * 32 + kb * 8 + jp * 2;
    cv.u[jp] = pk2(W1[k * 128 + h], W1[(k + 1) * 128 + h]);
  }
  frag_out[fid] = cv.s8;
}

// ---- k1: fused kernel, one block per b; W1 frags in 32 KB LDS. ----
__global__ __launch_bounds__(256, 4) void m2o_attn_kernel(
    const float* __restrict__ input, const float* __restrict__ z,
    const int* __restrict__ mask, const float* __restrict__ W2,
    const float* __restrict__ b2, const float* __restrict__ V,
    const float* __restrict__ bV, const short8_t* __restrict__ frag,
    float* __restrict__ out) {
  __shared__ short8_t frag_lds[2048];    // 32 KB: [nh(8)][kk(4)][lane(64)] — FULL table
  __shared__ float w2h_part[2][128];
  __shared__ float att_part[2][SP];
  __shared__ float att_w[SP];
  __shared__ float pool[2][128];
  __shared__ float redA[4], redB[4];

  const int t = threadIdx.x;
  const int b = blockIdx.x;
  const int lane = t & 63;
  const int wid = t >> 6;
  const int c = lane & 15;      // MFMA col lane
  const int kb = lane >> 4;     // k-block 0..3

  const float* inb = input + (size_t)b * (S_ * 128);

  // stage the full 2048-entry fragment table (8 x 256 coalesced 16B loads)
  #pragma unroll
  for (int i = 0; i < 8; ++i) frag_lds[t + i * 256] = frag[t + i * 256];

  // hoist mask + bV into registers
  const int maskv = (t < S_) ? mask[(size_t)b * S_ + t] : 0;
  const float bVv = bV[0];

  // w2h partials: thread t = (K-half ph) x (col h)
  {
    const int h = t & 127, ph = t >> 7;
    const float* zb = z + (size_t)b * 128 + ph * 64;
    float acc = (ph == 0) ? b2[h] : 0.f;
    #pragma unroll 8
    for (int d = 0; d < 64; ++d) acc = fmaf(zb[d], W2[(ph * 64 + d) * 128 + h], acc);
    w2h_part[ph][h] = acc;
  }

  const int hh_i = wid & 1, hh = hh_i * 64;
  float vv[4];
  #pragma unroll
  for (int n = 0; n < 4; ++n) vv[n] = V[hh + n * 16 + c];

  __syncthreads();

  float w2v[4];
  #pragma unroll
  for (int n = 0; n < 4; ++n) {
    const int h = hh + n * 16 + c;
    w2v[n] = w2h_part[0][h] + w2h_part[1][h];
  }

  // main loop: wave = (row-half) x (h-half); A from global w/ one-tile prefetch
  const int half = wid >> 1;
  const int mt0 = half * 7;
  const int nmt = half ? 6 : 7;

  float4 pa[4][2];
  {
    const int arow = mt0 * 16 + c;
    const int lrow = arow < S_ ? arow : (S_ - 1);
    const float* rp = inb + lrow * 128 + kb * 8;
    #pragma unroll
    for (int kk = 0; kk < 4; ++kk) {
      pa[kk][0] = *reinterpret_cast<const float4*>(rp + kk * 32);
      pa[kk][1] = *reinterpret_cast<const float4*>(rp + kk * 32 + 4);
    }
  }

  for (int i = 0; i < nmt; ++i) {
    const int mt = mt0 + i;
    // convert prefetched A to bf16 frags
    short8_t a[4];
    #pragma unroll
    for (int kk = 0; kk < 4; ++kk) {
      union { short8_t s8; unsigned int u[4]; } cv;
      cv.u[0] = pk2(pa[kk][0].x, pa[kk][0].y);
      cv.u[1] = pk2(pa[kk][0].z, pa[kk][0].w);
      cv.u[2] = pk2(pa[kk][1].x, pa[kk][1].y);
      cv.u[3] = pk2(pa[kk][1].z, pa[kk][1].w);
      a[kk] = cv.s8;
    }
    // prefetch next mt tile
    if (i + 1 < nmt) {
      const int arow = (mt + 1) * 16 + c;
      const int lrow = arow < S_ ? arow : (S_ - 1);
      const float* rp = inb + lrow * 128 + kb * 8;
      #pragma unroll
      for (int kk = 0; kk < 4; ++kk) {
        pa[kk][0] = *reinterpret_cast<const float4*>(rp + kk * 32);
        pa[kk][1] = *reinterpret_cast<const float4*>(rp + kk * 32 + 4);
      }
    }
    float4_t acc[4] = {{0.f, 0.f, 0.f, 0.f}, {0.f, 0.f, 0.f, 0.f},
                       {0.f, 0.f, 0.f, 0.f}, {0.f, 0.f, 0.f, 0.f}};
    #pragma unroll
    for (int kk = 0; kk < 4; ++kk) {
      #pragma unroll
      for (int n = 0; n < 4; ++n)
        acc[n] = __builtin_amdgcn_mfma_f32_16x16x32_bf16(
            a[kk], frag_lds[((hh_i * 4 + n) * 4 + kk) * 64 + lane], acc[n], 0, 0, 0);
    }
    // fused tanh + V-dot; D layout: col = n*16+c, row = mt*16 + kb*4 + r
    #pragma unroll
    for (int r = 0; r < 4; ++r) {
      const int row = mt * 16 + kb * 4 + r;
      float p = 0.f;
      #pragma unroll
      for (int n = 0; n < 4; ++n) {
        const float x = acc[n][r] + w2v[n];
        const float e = __expf(x + x);            // inf-safe: u -> +/-1
        const float u = 1.f - __fdividef(2.f, e + 1.f);
        p = fmaf(u, vv[n], p);
      }
      p += __shfl_xor(p, 1);
      p += __shfl_xor(p, 2);
      p += __shfl_xor(p, 4);
      p += __shfl_xor(p, 8);
      if (c == 0 && row < S_) att_part[hh_i][row] = p;
    }
  }
  __syncthreads();

  // masked softmax over S
  float logit = -3.0e38f, ee = 0.f;
  if (t < S_) {
    logit = att_part[0][t] + att_part[1][t] + bVv;
    if (maskv == 0) logit = -1e10f;
  }
  {
    float m = logit;
    #pragma unroll
    for (int off = 32; off; off >>= 1) m = fmaxf(m, __shfl_xor(m, off));
    if (lane == 0) redA[wid] = m;
  }
  __syncthreads();
  {
    const float M = fmaxf(fmaxf(redA[0], redA[1]), fmaxf(redA[2], redA[3]));
    ee = (t < S_) ? __expf(logit - M) : 0.f;
    float sg = ee;
    #pragma unroll
    for (int off = 32; off; off >>= 1) sg += __shfl_xor(sg, off);
    if (lane == 0) redB[wid] = sg;
  }
  __syncthreads();
  {
    const float Ssum = redB[0] + redB[1] + redB[2] + redB[3];
    if (t < SP) att_w[t] = (t < S_) ? __fdividef(ee, Ssum) : 0.f;
  }
  __syncthreads();

  // pooling: out[b][d] = sum_s att_w[s] * input[b][s][d] (global re-read, L2/L3)
  {
    const int d = t & 127, ph = t >> 7;
    const float* pp = inb + (size_t)(ph * 100) * 128 + d;
    float a0 = 0.f;
    #pragma unroll 4
    for (int s = 0; s < 100; ++s) a0 = fmaf(att_w[ph * 100 + s], pp[s * 128], a0);
    pool[ph][d] = a0;
  }
  __syncthreads();
  if (t < 128) out[(size_t)b * 128 + t] = pool[0][t] + pool[1][t];
}

extern "C" void kernel_launch(void* const* d_in, const int* in_sizes, int n_in,
                              void* d_out, int out_size, void* d_ws, size_t ws_size,
                              hipStream_t stream) {
  const float* input = (const float*)d_in[0];
  const float* z     = (const float*)d_in[1];
  const int*   mask  = (const int*)d_in[2];
  const float* W1    = (const float*)d_in[3];
  const float* W2    = (const float*)d_in[4];
  const float* b2    = (const float*)d_in[5];
  const float* V     = (const float*)d_in[6];
  const float* bV    = (const float*)d_in[7];
  float* out = (float*)d_out;

  short8_t* frag_ws = (short8_t*)d_ws;   // 32 KB only
  prep_frag_kernel<<<8, 256, 0, stream>>>(W1, frag_ws);
  m2o_attn_kernel<<<1024, 256, 0, stream>>>(input, z, mask, W2, b2, V, bV,
                                            frag_ws, out);
}